// Round 7
// baseline (166.689 us; speedup 1.0000x reference)
//
#include <hip/hip_runtime.h>
#include <hip/hip_bf16.h>
#include <hip/hip_cooperative_groups.h>

namespace cg = cooperative_groups;

#define IM 1024
#define NSEG 128
#define EPSF 1e-10f
#define H 4
#define CG 257            // coarse grid: samples at x,y = 0,4,...,1024
#define NTOT (CG * CG)    // 66049 coarse samples
#define NBLK 512          // fused kernel grid
#define P1BLK ((NTOT + 255) / 256)  // 259 blocks carry phase-1 samples

// ws layout (floats):
//   [0]              bf16 flag (uint)
//   [64 .. 64+P1BLK) per-block min   (fallback path: per-fine-row, 1024)
//   [2048 .. +P1BLK) per-block max   (fallback: 1024)
//   [4096 .. +NTOT)  coarse template (~258 KB)
#define WS_FLAG 0
#define WS_BMIN 64
#define WS_BMAX 2048
#define WS_COARSE 4096

__device__ __forceinline__ float bf16_decode(unsigned short u) {
    return __uint_as_float(((unsigned)u) << 16);
}

// Per-segment constants in LDS:  cA = (dx, dy, x0, y0),  cB = (inv_d, c0n)
__device__ __forceinline__ int setup_consts(const void* xs_raw, const void* ys_raw,
                                            float4* cA, float2* cB,
                                            float* sx, float* sy, int* sflag) {
    int tx = threadIdx.x;
    if (tx == 0) *sflag = 1;
    __syncthreads();
    if (tx <= NSEG) {
        unsigned short ux = ((const unsigned short*)xs_raw)[tx];
        unsigned short uy = ((const unsigned short*)ys_raw)[tx];
        float fx = bf16_decode(ux), fy = bf16_decode(uy);
        bool plaus = (fx >= 0.0f) && (fx <= 1024.0f) && (fy >= 0.0f) && (fy <= 1024.0f);
        if (!plaus) atomicAnd(sflag, 0);
        sx[tx] = fx; sy[tx] = fy;
    }
    __syncthreads();
    int flag = *sflag;
    if (!flag && tx <= NSEG) {
        sx[tx] = ((const float*)xs_raw)[tx];
        sy[tx] = ((const float*)ys_raw)[tx];
    }
    __syncthreads();
    if (tx < NSEG) {
        float x0 = sx[tx], y0 = sy[tx], x1 = sx[tx + 1], y1 = sy[tx + 1];
        float dx = x1 - x0, dy = y1 - y0;
        float inv_d = 1.0f / (dx * dx + dy * dy + EPSF);
        float c0n = -(dx * x0 + dy * y0);
        cA[tx] = make_float4(dx, dy, x0, y0);
        cB[tx] = make_float2(inv_d, c0n);
    }
    __syncthreads();
    return flag;
}

// Fused: phase 1 = coarse field (1 sample/thread, flat), grid sync,
// phase 2 = global min/max + bilinear upsample (2 rows/block).
__global__ __launch_bounds__(256, 4) void k_fused(const void* __restrict__ xs_raw,
                                                  const void* __restrict__ ys_raw,
                                                  float* __restrict__ ws,
                                                  void* __restrict__ out) {
    __shared__ float4 cA[NSEG];
    __shared__ float2 cB[NSEG];
    __shared__ float sx[NSEG + 1], sy[NSEG + 1];
    __shared__ int sflag;
    __shared__ float swmn[4], swmx[4], sred[2];

    int tx = threadIdx.x;
    int bid = blockIdx.x;
    int g = bid * 256 + tx;
    bool p1_block = (bid < P1BLK);

    // ---- phase 1: coarse samples ----
    if (p1_block) {
        int flag = setup_consts(xs_raw, ys_raw, cA, cB, sx, sy, &sflag);
        if (bid == 0 && tx == 0) ((unsigned*)ws)[WS_FLAG] = (unsigned)flag;

        bool valid = (g < NTOT);
        int row = g / CG;
        int col = g - row * CG;
        float yp = (float)(row * H);
        float xp = (float)(col * H);
        float val = 0.0f;
#pragma unroll 8
        for (int s = 0; s < NSEG; ++s) {
            float4 A = cA[s];
            float2 B = cB[s];
            float rb = fmaf(A.y, yp, B.y);
            float t  = __builtin_amdgcn_fmed3f(fmaf(A.x, xp, rb) * B.x, 0.0f, 1.0f);
            float xc = fmaf(t, A.x, A.z), yc = fmaf(t, A.y, A.w);
            float ddx = xp - xc, ddy = yp - yc;
            val += __builtin_amdgcn_sqrtf(fmaf(ddx, ddx, fmaf(ddy, ddy, EPSF)));
        }
        if (valid) ws[WS_COARSE + g] = val;

        float vmn = valid ? val : 1e30f;
        float vmx = valid ? val : -1e30f;
        for (int off = 32; off > 0; off >>= 1) {
            vmn = fminf(vmn, __shfl_down(vmn, off));
            vmx = fmaxf(vmx, __shfl_down(vmx, off));
        }
        if ((tx & 63) == 0) { swmn[tx >> 6] = vmn; swmx[tx >> 6] = vmx; }
        __syncthreads();
        if (tx == 0) {
            float m = fminf(fminf(swmn[0], swmn[1]), fminf(swmn[2], swmn[3]));
            float M = fmaxf(fmaxf(swmx[0], swmx[1]), fmaxf(swmx[2], swmx[3]));
            ws[WS_BMIN + bid] = m;
            ws[WS_BMAX + bid] = M;
        }
    }

    __threadfence();
    cg::this_grid().sync();

    // ---- phase 2: global min/max, then upsample rows 2*bid, 2*bid+1 ----
    {
        float mn = 1e30f, mx = -1e30f;
        if (tx < P1BLK) {
            mn = ws[WS_BMIN + tx];
            mx = ws[WS_BMAX + tx];
        }
        if (tx + 256 < P1BLK) {
            mn = fminf(mn, ws[WS_BMIN + tx + 256]);
            mx = fmaxf(mx, ws[WS_BMAX + tx + 256]);
        }
        for (int off = 32; off > 0; off >>= 1) {
            mn = fminf(mn, __shfl_down(mn, off));
            mx = fmaxf(mx, __shfl_down(mx, off));
        }
        if ((tx & 63) == 0) { swmn[tx >> 6] = mn; swmx[tx >> 6] = mx; }
        __syncthreads();
        if (tx == 0) {
            float m = fminf(fminf(swmn[0], swmn[1]), fminf(swmn[2], swmn[3]));
            float M = fmaxf(fmaxf(swmx[0], swmx[1]), fmaxf(swmx[2], swmx[3]));
            sred[0] = m;
            sred[1] = 1.0f / (M - m);
        }
        __syncthreads();
    }
    float tmin = sred[0], scale = sred[1];
    int flag = (int)((const unsigned*)ws)[WS_FLAG];

#pragma unroll
    for (int r = 0; r < 2; ++r) {
        int y = 2 * bid + r;
        int y4 = y >> 2;
        float wy = (float)(y & 3) * 0.25f;
        const float* gp = ws + WS_COARSE + y4 * CG + tx;
        float c00 = gp[0], c01 = gp[1], c10 = gp[CG], c11 = gp[CG + 1];
        float a  = fmaf(wy, c10 - c00, c00);
        float b0 = c01 - c00, b1 = c11 - c10;
        float b  = fmaf(wy, b1 - b0, b0);
        float as = (a - tmin) * scale;
        float bs = b * scale;
        float r0 = as;
        float r1 = fmaf(bs, 0.25f, as);
        float r2 = fmaf(bs, 0.50f, as);
        float r3 = fmaf(bs, 0.75f, as);
        int idx = y * IM + 4 * tx;
        if (flag) {
            __hip_bfloat16 h0 = __float2bfloat16(r0);
            __hip_bfloat16 h1 = __float2bfloat16(r1);
            __hip_bfloat16 h2 = __float2bfloat16(r2);
            __hip_bfloat16 h3 = __float2bfloat16(r3);
            ushort4 p;
            p.x = *(unsigned short*)&h0; p.y = *(unsigned short*)&h1;
            p.z = *(unsigned short*)&h2; p.w = *(unsigned short*)&h3;
            *(ushort4*)((unsigned short*)out + idx) = p;
        } else {
            *(float4*)((float*)out + idx) = make_float4(r0, r1, r2, r3);
        }
    }
}

// ---------- fallback path (tiny ws): exact render, proven in R3 ----------
__device__ __forceinline__ void render4(const float4* cA, const float2* cB,
                                        float yp, float xp0, float acc[4]) {
    float a0 = 0.f, a1 = 0.f, a2 = 0.f, a3 = 0.f;
    float xp1 = xp0 + 256.f, xp2 = xp0 + 512.f, xp3 = xp0 + 768.f;
#pragma unroll 8
    for (int s = 0; s < NSEG; ++s) {
        float4 A = cA[s];
        float2 B = cB[s];
        float rb = fmaf(A.y, yp, B.y);
        {
            float t  = __builtin_amdgcn_fmed3f(fmaf(A.x, xp0, rb) * B.x, 0.0f, 1.0f);
            float xc = fmaf(t, A.x, A.z), yc = fmaf(t, A.y, A.w);
            float dx = xp0 - xc, dy = yp - yc;
            a0 += __builtin_amdgcn_sqrtf(fmaf(dx, dx, fmaf(dy, dy, EPSF)));
        }
        {
            float t  = __builtin_amdgcn_fmed3f(fmaf(A.x, xp1, rb) * B.x, 0.0f, 1.0f);
            float xc = fmaf(t, A.x, A.z), yc = fmaf(t, A.y, A.w);
            float dx = xp1 - xc, dy = yp - yc;
            a1 += __builtin_amdgcn_sqrtf(fmaf(dx, dx, fmaf(dy, dy, EPSF)));
        }
        {
            float t  = __builtin_amdgcn_fmed3f(fmaf(A.x, xp2, rb) * B.x, 0.0f, 1.0f);
            float xc = fmaf(t, A.x, A.z), yc = fmaf(t, A.y, A.w);
            float dx = xp2 - xc, dy = yp - yc;
            a2 += __builtin_amdgcn_sqrtf(fmaf(dx, dx, fmaf(dy, dy, EPSF)));
        }
        {
            float t  = __builtin_amdgcn_fmed3f(fmaf(A.x, xp3, rb) * B.x, 0.0f, 1.0f);
            float xc = fmaf(t, A.x, A.z), yc = fmaf(t, A.y, A.w);
            float dx = xp3 - xc, dy = yp - yc;
            a3 += __builtin_amdgcn_sqrtf(fmaf(dx, dx, fmaf(dy, dy, EPSF)));
        }
    }
    acc[0] = a0; acc[1] = a1; acc[2] = a2; acc[3] = a3;
}

__global__ __launch_bounds__(256, 4) void k_render_minmax(const void* __restrict__ xs_raw,
                                                          const void* __restrict__ ys_raw,
                                                          float* __restrict__ ws) {
    __shared__ float4 cA[NSEG];
    __shared__ float2 cB[NSEG];
    __shared__ float sx[NSEG + 1], sy[NSEG + 1];
    __shared__ int sflag;
    __shared__ float swmn[4], swmx[4];
    int tx = threadIdx.x;
    int y = blockIdx.x;
    int flag = setup_consts(xs_raw, ys_raw, cA, cB, sx, sy, &sflag);
    float acc[4];
    render4(cA, cB, (float)y, (float)tx, acc);
    float tmn = fminf(fminf(acc[0], acc[1]), fminf(acc[2], acc[3]));
    float tmx = fmaxf(fmaxf(acc[0], acc[1]), fmaxf(acc[2], acc[3]));
    for (int off = 32; off > 0; off >>= 1) {
        tmn = fminf(tmn, __shfl_down(tmn, off));
        tmx = fmaxf(tmx, __shfl_down(tmx, off));
    }
    if ((tx & 63) == 0) { swmn[tx >> 6] = tmn; swmx[tx >> 6] = tmx; }
    __syncthreads();
    if (tx == 0) {
        float m = fminf(fminf(swmn[0], swmn[1]), fminf(swmn[2], swmn[3]));
        float M = fmaxf(fmaxf(swmx[0], swmx[1]), fmaxf(swmx[2], swmx[3]));
        ws[WS_BMIN + y] = m;
        ws[WS_BMAX + y] = M;
        if (y == 0) ((unsigned*)ws)[WS_FLAG] = (unsigned)flag;
    }
}

__global__ __launch_bounds__(256, 4) void k_norm_recompute(const void* __restrict__ xs_raw,
                                                           const void* __restrict__ ys_raw,
                                                           const float* __restrict__ ws,
                                                           void* __restrict__ out) {
    __shared__ float4 cA[NSEG];
    __shared__ float2 cB[NSEG];
    __shared__ float sx[NSEG + 1], sy[NSEG + 1];
    __shared__ int sflag;
    __shared__ float swmn[4], swmx[4], sred[2];
    int tx = threadIdx.x;
    int y = blockIdx.x;
    int flag = setup_consts(xs_raw, ys_raw, cA, cB, sx, sy, &sflag);
    float mn = 1e30f, mx = -1e30f;
#pragma unroll
    for (int i = 0; i < 4; ++i) {
        mn = fminf(mn, ws[WS_BMIN + tx + 256 * i]);
        mx = fmaxf(mx, ws[WS_BMAX + tx + 256 * i]);
    }
    for (int off = 32; off > 0; off >>= 1) {
        mn = fminf(mn, __shfl_down(mn, off));
        mx = fmaxf(mx, __shfl_down(mx, off));
    }
    if ((tx & 63) == 0) { swmn[tx >> 6] = mn; swmx[tx >> 6] = mx; }
    __syncthreads();
    if (tx == 0) {
        float m = fminf(fminf(swmn[0], swmn[1]), fminf(swmn[2], swmn[3]));
        float M = fmaxf(fmaxf(swmx[0], swmx[1]), fmaxf(swmx[2], swmx[3]));
        sred[0] = m; sred[1] = 1.0f / (M - m);
    }
    __syncthreads();
    float tmin = sred[0], scale = sred[1];
    float acc[4];
    render4(cA, cB, (float)y, (float)tx, acc);
#pragma unroll
    for (int k = 0; k < 4; ++k) {
        float r = (acc[k] - tmin) * scale;
        int idx = y * IM + tx + 256 * k;
        if (flag) {
            __hip_bfloat16 h = __float2bfloat16(r);
            ((unsigned short*)out)[idx] = *(unsigned short*)&h;
        } else {
            ((float*)out)[idx] = r;
        }
    }
}

extern "C" void kernel_launch(void* const* d_in, const int* in_sizes, int n_in,
                              void* d_out, int out_size, void* d_ws, size_t ws_size,
                              hipStream_t stream) {
    const void* xs = d_in[0];
    const void* ys = d_in[1];
    float* wsf = (float*)d_ws;
    bool coarse_ok = ws_size >= (size_t)(WS_COARSE + NTOT + 64) * sizeof(float);

    if (coarse_ok) {
        void* args[] = { (void*)&xs, (void*)&ys, (void*)&wsf, (void*)&d_out };
        hipLaunchCooperativeKernel((const void*)k_fused, dim3(NBLK), dim3(256),
                                   args, 0, stream);
    } else {
        hipLaunchKernelGGL(k_render_minmax, dim3(IM), dim3(256), 0, stream, xs, ys, wsf);
        hipLaunchKernelGGL(k_norm_recompute, dim3(IM), dim3(256), 0, stream,
                           xs, ys, wsf, d_out);
    }
}

// Round 8
// 65.054 us; speedup vs baseline: 2.5623x; 2.5623x over previous
//
#include <hip/hip_runtime.h>
#include <hip/hip_bf16.h>

#define IM 1024
#define NSEG 128
#define EPSF 1e-10f
#define H 4
#define CG 257            // coarse grid: samples at x,y = 0,4,...,1024
#define NTOT (CG * CG)    // 66049 coarse samples
#define P1BLK ((NTOT + 255) / 256)  // 259 coarse blocks

// ws layout (floats):
//   [0]              bf16 flag (uint)
//   [64 .. 64+P1BLK) per-block min   (fallback path: per-fine-row, 1024)
//   [2048 .. +P1BLK) per-block max   (fallback: 1024)
//   [4096 .. +NTOT)  coarse template (~258 KB)
#define WS_FLAG 0
#define WS_BMIN 64
#define WS_BMAX 2048
#define WS_COARSE 4096

__device__ __forceinline__ float bf16_decode(unsigned short u) {
    return __uint_as_float(((unsigned)u) << 16);
}

// Per-segment constants in LDS:  cA = (dx, dy, x0, y0),  cB = (inv_d, c0n)
__device__ __forceinline__ int setup_consts(const void* xs_raw, const void* ys_raw,
                                            float4* cA, float2* cB,
                                            float* sx, float* sy, int* sflag) {
    int tx = threadIdx.x;
    if (tx == 0) *sflag = 1;
    __syncthreads();
    if (tx <= NSEG) {
        unsigned short ux = ((const unsigned short*)xs_raw)[tx];
        unsigned short uy = ((const unsigned short*)ys_raw)[tx];
        float fx = bf16_decode(ux), fy = bf16_decode(uy);
        bool plaus = (fx >= 0.0f) && (fx <= 1024.0f) && (fy >= 0.0f) && (fy <= 1024.0f);
        if (!plaus) atomicAnd(sflag, 0);
        sx[tx] = fx; sy[tx] = fy;
    }
    __syncthreads();
    int flag = *sflag;
    if (!flag && tx <= NSEG) {
        sx[tx] = ((const float*)xs_raw)[tx];
        sy[tx] = ((const float*)ys_raw)[tx];
    }
    __syncthreads();
    if (tx < NSEG) {
        float x0 = sx[tx], y0 = sy[tx], x1 = sx[tx + 1], y1 = sy[tx + 1];
        float dx = x1 - x0, dy = y1 - y0;
        float inv_d = 1.0f / (dx * dx + dy * dy + EPSF);
        float c0n = -(dx * x0 + dy * y0);
        cA[tx] = make_float4(dx, dy, x0, y0);
        cB[tx] = make_float2(inv_d, c0n);
    }
    __syncthreads();
    return flag;
}

// Coarse render: flat 1 sample/thread, 259 blocks x 256. Branchless R3 math.
__global__ __launch_bounds__(256, 4) void k_coarse(const void* __restrict__ xs_raw,
                                                   const void* __restrict__ ys_raw,
                                                   float* __restrict__ ws) {
    __shared__ float4 cA[NSEG];
    __shared__ float2 cB[NSEG];
    __shared__ float sx[NSEG + 1], sy[NSEG + 1];
    __shared__ int sflag;
    __shared__ float swmn[4], swmx[4];

    int tx = threadIdx.x;
    int bid = blockIdx.x;
    int g = bid * 256 + tx;
    int flag = setup_consts(xs_raw, ys_raw, cA, cB, sx, sy, &sflag);
    if (bid == 0 && tx == 0) ((unsigned*)ws)[WS_FLAG] = (unsigned)flag;

    bool valid = (g < NTOT);
    int row = g / CG;
    int col = g - row * CG;
    float yp = (float)(row * H);
    float xp = (float)(col * H);
    float val = 0.0f;
#pragma unroll 8
    for (int s = 0; s < NSEG; ++s) {
        float4 A = cA[s];
        float2 B = cB[s];
        float rb = fmaf(A.y, yp, B.y);
        float t  = __builtin_amdgcn_fmed3f(fmaf(A.x, xp, rb) * B.x, 0.0f, 1.0f);
        float xc = fmaf(t, A.x, A.z), yc = fmaf(t, A.y, A.w);
        float ddx = xp - xc, ddy = yp - yc;
        val += __builtin_amdgcn_sqrtf(fmaf(ddx, ddx, fmaf(ddy, ddy, EPSF)));
    }
    if (valid) ws[WS_COARSE + g] = val;

    float vmn = valid ? val : 1e30f;
    float vmx = valid ? val : -1e30f;
    for (int off = 32; off > 0; off >>= 1) {
        vmn = fminf(vmn, __shfl_down(vmn, off));
        vmx = fmaxf(vmx, __shfl_down(vmx, off));
    }
    if ((tx & 63) == 0) { swmn[tx >> 6] = vmn; swmx[tx >> 6] = vmx; }
    __syncthreads();
    if (tx == 0) {
        float m = fminf(fminf(swmn[0], swmn[1]), fminf(swmn[2], swmn[3]));
        float M = fmaxf(fmaxf(swmx[0], swmx[1]), fmaxf(swmx[2], swmx[3]));
        ws[WS_BMIN + bid] = m;
        ws[WS_BMAX + bid] = M;
    }
}

// Upsample: global minmax over 259 block-extrema, bilinear, normalize, store.
__global__ __launch_bounds__(256) void k_up(const float* __restrict__ ws,
                                            void* __restrict__ out) {
    __shared__ float swmn[4], swmx[4], sred[2];
    int tx = threadIdx.x;
    float mn = 1e30f, mx = -1e30f;
    if (tx < P1BLK) {
        mn = ws[WS_BMIN + tx];
        mx = ws[WS_BMAX + tx];
    }
    if (tx + 256 < P1BLK) {
        mn = fminf(mn, ws[WS_BMIN + tx + 256]);
        mx = fmaxf(mx, ws[WS_BMAX + tx + 256]);
    }
    for (int off = 32; off > 0; off >>= 1) {
        mn = fminf(mn, __shfl_down(mn, off));
        mx = fmaxf(mx, __shfl_down(mx, off));
    }
    if ((tx & 63) == 0) { swmn[tx >> 6] = mn; swmx[tx >> 6] = mx; }
    __syncthreads();
    if (tx == 0) {
        float m = fminf(fminf(swmn[0], swmn[1]), fminf(swmn[2], swmn[3]));
        float M = fmaxf(fmaxf(swmx[0], swmx[1]), fmaxf(swmx[2], swmx[3]));
        sred[0] = m;
        sred[1] = 1.0f / (M - m);
    }
    __syncthreads();
    float tmin = sred[0], scale = sred[1];
    int flag = (int)((const unsigned*)ws)[WS_FLAG];

    int y = blockIdx.x;
    int y4 = y >> 2;
    float wy = (float)(y & 3) * 0.25f;
    const float* g = ws + WS_COARSE + y4 * CG + tx;
    float c00 = g[0], c01 = g[1], c10 = g[CG], c11 = g[CG + 1];
    float a  = fmaf(wy, c10 - c00, c00);
    float b0 = c01 - c00, b1 = c11 - c10;
    float b  = fmaf(wy, b1 - b0, b0);
    float as = (a - tmin) * scale;
    float bs = b * scale;
    float r0 = as;
    float r1 = fmaf(bs, 0.25f, as);
    float r2 = fmaf(bs, 0.50f, as);
    float r3 = fmaf(bs, 0.75f, as);
    int idx = y * IM + 4 * tx;
    if (flag) {
        __hip_bfloat16 h0 = __float2bfloat16(r0);
        __hip_bfloat16 h1 = __float2bfloat16(r1);
        __hip_bfloat16 h2 = __float2bfloat16(r2);
        __hip_bfloat16 h3 = __float2bfloat16(r3);
        ushort4 p;
        p.x = *(unsigned short*)&h0; p.y = *(unsigned short*)&h1;
        p.z = *(unsigned short*)&h2; p.w = *(unsigned short*)&h3;
        *(ushort4*)((unsigned short*)out + idx) = p;
    } else {
        *(float4*)((float*)out + idx) = make_float4(r0, r1, r2, r3);
    }
}

// ---------- fallback path (tiny ws): exact render, proven in R3 ----------
__device__ __forceinline__ void render4(const float4* cA, const float2* cB,
                                        float yp, float xp0, float acc[4]) {
    float a0 = 0.f, a1 = 0.f, a2 = 0.f, a3 = 0.f;
    float xp1 = xp0 + 256.f, xp2 = xp0 + 512.f, xp3 = xp0 + 768.f;
#pragma unroll 8
    for (int s = 0; s < NSEG; ++s) {
        float4 A = cA[s];
        float2 B = cB[s];
        float rb = fmaf(A.y, yp, B.y);
        {
            float t  = __builtin_amdgcn_fmed3f(fmaf(A.x, xp0, rb) * B.x, 0.0f, 1.0f);
            float xc = fmaf(t, A.x, A.z), yc = fmaf(t, A.y, A.w);
            float dx = xp0 - xc, dy = yp - yc;
            a0 += __builtin_amdgcn_sqrtf(fmaf(dx, dx, fmaf(dy, dy, EPSF)));
        }
        {
            float t  = __builtin_amdgcn_fmed3f(fmaf(A.x, xp1, rb) * B.x, 0.0f, 1.0f);
            float xc = fmaf(t, A.x, A.z), yc = fmaf(t, A.y, A.w);
            float dx = xp1 - xc, dy = yp - yc;
            a1 += __builtin_amdgcn_sqrtf(fmaf(dx, dx, fmaf(dy, dy, EPSF)));
        }
        {
            float t  = __builtin_amdgcn_fmed3f(fmaf(A.x, xp2, rb) * B.x, 0.0f, 1.0f);
            float xc = fmaf(t, A.x, A.z), yc = fmaf(t, A.y, A.w);
            float dx = xp2 - xc, dy = yp - yc;
            a2 += __builtin_amdgcn_sqrtf(fmaf(dx, dx, fmaf(dy, dy, EPSF)));
        }
        {
            float t  = __builtin_amdgcn_fmed3f(fmaf(A.x, xp3, rb) * B.x, 0.0f, 1.0f);
            float xc = fmaf(t, A.x, A.z), yc = fmaf(t, A.y, A.w);
            float dx = xp3 - xc, dy = yp - yc;
            a3 += __builtin_amdgcn_sqrtf(fmaf(dx, dx, fmaf(dy, dy, EPSF)));
        }
    }
    acc[0] = a0; acc[1] = a1; acc[2] = a2; acc[3] = a3;
}

__global__ __launch_bounds__(256, 4) void k_render_minmax(const void* __restrict__ xs_raw,
                                                          const void* __restrict__ ys_raw,
                                                          float* __restrict__ ws) {
    __shared__ float4 cA[NSEG];
    __shared__ float2 cB[NSEG];
    __shared__ float sx[NSEG + 1], sy[NSEG + 1];
    __shared__ int sflag;
    __shared__ float swmn[4], swmx[4];
    int tx = threadIdx.x;
    int y = blockIdx.x;
    int flag = setup_consts(xs_raw, ys_raw, cA, cB, sx, sy, &sflag);
    float acc[4];
    render4(cA, cB, (float)y, (float)tx, acc);
    float tmn = fminf(fminf(acc[0], acc[1]), fminf(acc[2], acc[3]));
    float tmx = fmaxf(fmaxf(acc[0], acc[1]), fmaxf(acc[2], acc[3]));
    for (int off = 32; off > 0; off >>= 1) {
        tmn = fminf(tmn, __shfl_down(tmn, off));
        tmx = fmaxf(tmx, __shfl_down(tmx, off));
    }
    if ((tx & 63) == 0) { swmn[tx >> 6] = tmn; swmx[tx >> 6] = tmx; }
    __syncthreads();
    if (tx == 0) {
        float m = fminf(fminf(swmn[0], swmn[1]), fminf(swmn[2], swmn[3]));
        float M = fmaxf(fmaxf(swmx[0], swmx[1]), fmaxf(swmx[2], swmx[3]));
        ws[WS_BMIN + y] = m;
        ws[WS_BMAX + y] = M;
        if (y == 0) ((unsigned*)ws)[WS_FLAG] = (unsigned)flag;
    }
}

__global__ __launch_bounds__(256, 4) void k_norm_recompute(const void* __restrict__ xs_raw,
                                                           const void* __restrict__ ys_raw,
                                                           const float* __restrict__ ws,
                                                           void* __restrict__ out) {
    __shared__ float4 cA[NSEG];
    __shared__ float2 cB[NSEG];
    __shared__ float sx[NSEG + 1], sy[NSEG + 1];
    __shared__ int sflag;
    __shared__ float swmn[4], swmx[4], sred[2];
    int tx = threadIdx.x;
    int y = blockIdx.x;
    int flag = setup_consts(xs_raw, ys_raw, cA, cB, sx, sy, &sflag);
    float mn = 1e30f, mx = -1e30f;
#pragma unroll
    for (int i = 0; i < 4; ++i) {
        mn = fminf(mn, ws[WS_BMIN + tx + 256 * i]);
        mx = fmaxf(mx, ws[WS_BMAX + tx + 256 * i]);
    }
    for (int off = 32; off > 0; off >>= 1) {
        mn = fminf(mn, __shfl_down(mn, off));
        mx = fmaxf(mx, __shfl_down(mx, off));
    }
    if ((tx & 63) == 0) { swmn[tx >> 6] = mn; swmx[tx >> 6] = mx; }
    __syncthreads();
    if (tx == 0) {
        float m = fminf(fminf(swmn[0], swmn[1]), fminf(swmn[2], swmn[3]));
        float M = fmaxf(fmaxf(swmx[0], swmx[1]), fmaxf(swmx[2], swmx[3]));
        sred[0] = m; sred[1] = 1.0f / (M - m);
    }
    __syncthreads();
    float tmin = sred[0], scale = sred[1];
    float acc[4];
    render4(cA, cB, (float)y, (float)tx, acc);
#pragma unroll
    for (int k = 0; k < 4; ++k) {
        float r = (acc[k] - tmin) * scale;
        int idx = y * IM + tx + 256 * k;
        if (flag) {
            __hip_bfloat16 h = __float2bfloat16(r);
            ((unsigned short*)out)[idx] = *(unsigned short*)&h;
        } else {
            ((float*)out)[idx] = r;
        }
    }
}

extern "C" void kernel_launch(void* const* d_in, const int* in_sizes, int n_in,
                              void* d_out, int out_size, void* d_ws, size_t ws_size,
                              hipStream_t stream) {
    const void* xs = d_in[0];
    const void* ys = d_in[1];
    float* wsf = (float*)d_ws;
    bool coarse_ok = ws_size >= (size_t)(WS_COARSE + NTOT + 64) * sizeof(float);

    if (coarse_ok) {
        hipLaunchKernelGGL(k_coarse, dim3(P1BLK), dim3(256), 0, stream, xs, ys, wsf);
        hipLaunchKernelGGL(k_up, dim3(IM), dim3(256), 0, stream, wsf, d_out);
    } else {
        hipLaunchKernelGGL(k_render_minmax, dim3(IM), dim3(256), 0, stream, xs, ys, wsf);
        hipLaunchKernelGGL(k_norm_recompute, dim3(IM), dim3(256), 0, stream,
                           xs, ys, wsf, d_out);
    }
}